// Round 7
// baseline (284.030 us; speedup 1.0000x reference)
//
#include <hip/hip_runtime.h>
#include <hip/hip_bf16.h>

typedef __attribute__((ext_vector_type(8))) short short8;
typedef __attribute__((ext_vector_type(4))) short short4v;
typedef __attribute__((ext_vector_type(16))) float floatx16;

#define Bn 32
#define Ln 512
#define Cn 300
#define Hn 512
#define Nn (Bn*Ln)          // 16384
#define XBP 518             // 512 + 3 halo each side
#define XBC 320             // channels padded to 10*32
#define HK 1216             // 4 convs x 304 (300 + 4 pad), 16-aligned slices
#define XST 328             // LDS x row stride in shorts: 164 words === 4 mod 32, conflict-free

#define XROWS 70            // 64 n-rows + 6 halo
#define XSZ (XROWS*XST)     // 22,960 shorts = 45,920 B -> 2 blocks/CU possible

// workspace layout in bf16 elements
#define XB_ELEMS (Bn*XBP*XBC)            // 5,304,320
#define WB_ELEMS 1331200                  // frag-major conv weights (m64-granular)
#define WC_ELEMS (Hn*HK)                  // 622,592
#define XB_OFF 0
#define WB_OFF (XB_OFF + XB_ELEMS)
#define WC_OFF (WB_OFF + WB_ELEMS)
#define HB_OFF (WC_OFF + WC_ELEMS)
// conv weight bases within WB (shorts): c1 @0 (102400), c2 @102400 (204800),
// c3 @307200 (307200), c7 @614400 (716800); per conv per m64: T*20480

__device__ __forceinline__ float fast_tanh(float x) {
    float ax = __builtin_fabsf(x);
    float t  = __expf(-2.f * ax);
    float r  = __builtin_fmaf(-2.f * t, __frcp_rn(1.f + t), 1.f);  // (1-t)/(1+t)
    return __builtin_copysignf(r, x);
}

// ---------------- merged prep kernel ----------------
__global__ void prep_all(const float* __restrict__ x,
                         const float* __restrict__ w1, const float* __restrict__ w2,
                         const float* __restrict__ w3, const float* __restrict__ w7,
                         const float* __restrict__ slp_w,
                         __hip_bfloat16* __restrict__ wsb) {
    int idx = blockIdx.x * 256 + threadIdx.x;
    if (idx < XB_ELEMS) {
        int c = idx % XBC;
        int t = idx / XBC;
        int p = t % XBP;
        int b = t / XBP;
        int l = p - 3;
        l = l < 0 ? 0 : (l > Ln - 1 ? Ln - 1 : l);   // replication pad
        float v = (c < Cn) ? x[(b * Ln + l) * Cn + c] : 0.f;
        wsb[idx] = __float2bfloat16(v);
    } else if (idx < WB_OFF + WB_ELEMS) {
        // frag-major conv weights: per conv, ((m64*T + tap)*20 + k16)*2 frags of 512
        int r = idx - WB_OFF, taps; const float* w;
        if (r < 102400)       { taps = 1; w = w1; }
        else if (r < 307200)  { taps = 2; w = w2; r -= 102400; }
        else if (r < 614400)  { taps = 3; w = w3; r -= 307200; }
        else                  { taps = 7; w = w7; r -= 614400; }
        int e    = r & 7;
        int lane = (r >> 3) & 63;
        int mq   = (r >> 9) & 1;
        int rest = r >> 10;
        int k16  = rest % 20;
        int rt   = rest / 20;
        int tap  = rt % taps;
        int m64  = rt / taps;
        int m = m64 * 64 + mq * 32 + (lane & 31);
        int c = k16 * 16 + (lane >> 5) * 8 + e;
        float v = (m < Cn && c < Cn) ? w[(m * Cn + c) * taps + tap] : 0.f;
        wsb[idx] = __float2bfloat16(v);
    } else if (idx < WC_OFF + WC_ELEMS) {
        int r = idx - WC_OFF;
        int e    = r & 7;
        int lane = (r >> 3) & 63;
        int f    = (r >> 9) & 15;
        int mc   = r >> 13;
        int ch   = mc % 19;
        int mt4  = mc / 19;
        int ks = f >> 2, mq = f & 3;
        int h = mt4 * 128 + mq * 32 + (lane & 31);
        int k = ch * 64 + ks * 16 + (lane >> 5) * 8 + e;   // 0..1215
        int cid = k / 304;
        int mk  = k - cid * 304;
        const float* row = slp_w + h * 1500;
        float v = 0.f;
        if (mk < 300) {
            if (cid == 0)      v = row[mk];
            else if (cid == 1) v = row[300 + mk];
            else if (cid == 2) v = row[600 + mk] + row[900 + mk];   // x3 + x5 fold
            else               v = row[1200 + mk];
        }
        wsb[idx] = __float2bfloat16(v);
    }
}

#define MFMA __builtin_amdgcn_mfma_f32_32x32x16_bf16

// ---------------- conv item: one (conv, m64-chunk) for this wave ----------------
// wave tile 64n x 64m, acc 2x2. Weights stream from global (frag-major, ping-pong
// indexed one step ahead -> waits are vmcnt(2), never a drain). x read from
// resident LDS tile (no barriers). Epilogue: frag-major hbuf, 8B stores.
template<int T, int LEAD>
__device__ __forceinline__ void conv_item(
        const short* __restrict__ xs, const short* __restrict__ wconv, int m64,
        const float* __restrict__ bias, int cid, int nt,
        short* __restrict__ hbuf, int lane, int lr, int oct) {
    const short* wp = wconv + m64 * (T * 20480);

    floatx16 acc[2][2];   // [mq][ni]
#pragma unroll
    for (int i = 0; i < 2; i++)
#pragma unroll
        for (int j = 0; j < 2; j++)
#pragma unroll
            for (int r = 0; r < 16; r++) acc[i][j][r] = 0.f;

    short8 wf[2][2];
    wf[0][0] = *(const short8*)&wp[lane * 8];
    wf[0][1] = *(const short8*)&wp[512 + lane * 8];
    const short* wnext = wp + 1024;

    for (int tap = 0; tap < T; ++tap) {
        const int vbase = (lr + tap - LEAD + 3) * XST + oct * 8;
#pragma unroll
        for (int k16 = 0; k16 < 20; ++k16) {
            const int p = k16 & 1;
            // prefetch next step's weight frags (last one overshoots into WC region: harmless)
            wf[p ^ 1][0] = *(const short8*)&wnext[lane * 8];
            wf[p ^ 1][1] = *(const short8*)&wnext[512 + lane * 8];
            wnext += 1024;
            short8 a0 = *(const short8*)&xs[vbase + k16 * 16];
            short8 a1 = *(const short8*)&xs[vbase + 32 * XST + k16 * 16];
            acc[0][0] = MFMA(wf[p][0], a0, acc[0][0], 0, 0, 0);
            acc[0][1] = MFMA(wf[p][0], a1, acc[0][1], 0, 0, 0);
            acc[1][0] = MFMA(wf[p][1], a0, acc[1][0], 0, 0, 0);
            acc[1][1] = MFMA(wf[p][1], a1, acc[1][1], 0, 0, 0);
        }
    }

    // epilogue: D rows = m (regs), cols = n (lane&31); frag-major hbuf
#pragma unroll
    for (int mq = 0; mq < 2; ++mq)
#pragma unroll
        for (int ni = 0; ni < 2; ++ni) {
            floatx16 v = acc[mq][ni];
#pragma unroll
            for (int q = 0; q < 4; ++q) {
                int mb = m64 * 64 + mq * 32 + q * 8 + oct * 4;
                if (mb < Cn) {
                    float4 bv = *(const float4*)&bias[mb];
                    short4v pk;
                    pk[0] = ((__hip_bfloat16_raw)__float2bfloat16(fast_tanh(v[q*4+0] + bv.x))).x;
                    pk[1] = ((__hip_bfloat16_raw)__float2bfloat16(fast_tanh(v[q*4+1] + bv.y))).x;
                    pk[2] = ((__hip_bfloat16_raw)__float2bfloat16(fast_tanh(v[q*4+2] + bv.z))).x;
                    pk[3] = ((__hip_bfloat16_raw)__float2bfloat16(fast_tanh(v[q*4+3] + bv.w))).x;
                    int k0  = cid * 304 + mb;
                    int off = ((nt * 2 + ni) * 76 + (k0 >> 4)) * 512
                              + (lr + ((q & 1) << 5)) * 8 + (oct << 2);
                    *(short4v*)&hbuf[off] = pk;
                }
            }
        }
}

// ---------------- conv kernel ----------------
// grid 256 (one 64-row n-tile per block), 256 threads = 4 waves.
// x-tile resident in LDS (loaded once, ONE barrier); waves run cost-balanced
// static item lists over the 20 (conv, m64) work items.
__global__ __launch_bounds__(256, 2) void conv_kernel(
        const __hip_bfloat16* __restrict__ xbg, const __hip_bfloat16* __restrict__ Wbg,
        const float* __restrict__ bias1, const float* __restrict__ bias2,
        const float* __restrict__ bias3, const float* __restrict__ bias7,
        __hip_bfloat16* __restrict__ hbuf) {
    __shared__ __align__(16) short xs[XSZ];

    const int tid  = threadIdx.x;
    const int lane = tid & 63;
    const int wave = tid >> 6;
    const int lr   = lane & 31;
    const int oct  = lane >> 5;

    const int nt = blockIdx.x;
    const int b  = nt >> 3;
    const int l0 = (nt & 7) << 6;
    const short* xbs = (const short*)xbg + (b * XBP + l0) * XBC;  // row r <-> l = l0 + r - 3
    const short* wb  = (const short*)Wbg;
    short* hb = (short*)hbuf;

    // stage x-tile: 70 rows x 320 shorts (contiguous in global) -> stride-328 LDS
#pragma unroll
    for (int i = 0; i < 11; ++i) {
        int j = tid + 256 * i;
        if (i < 10 || j < 2800) {
            int row = j / 40, g = j % 40;
            *(short8*)&xs[row * XST + g * 8] = *(const short8*)&xbs[row * XBC + g * 8];
        }
    }
    __syncthreads();   // the only barrier

    // item schedule: val = cid*8 + m64 (cid: 0=c1,1=c2,2=c3,3=c7), 5 bits each
    // w0: c7m0,c7m1,c2m0 (16u)  w1: c7m2,c7m3,c2m1 (16u)
    // w2: c7m4,c3m0,c3m1,c2m2,c1m0 (16u)
    // w3: c3m2,c3m3,c3m4,c2m3,c2m4,c1m1..c1m4 (17u)
    unsigned long long s;
    int cnt;
    if (wave == 0)      { s = 24ull | (25ull << 5) | (8ull << 10); cnt = 3; }
    else if (wave == 1) { s = 26ull | (27ull << 5) | (9ull << 10); cnt = 3; }
    else if (wave == 2) { s = 28ull | (16ull << 5) | (17ull << 10) | (10ull << 15) | (0ull << 20); cnt = 5; }
    else                { s = 18ull | (19ull << 5) | (20ull << 10) | (11ull << 15) | (12ull << 20)
                            | (1ull << 25) | (2ull << 30) | (3ull << 35) | (4ull << 40); cnt = 9; }

    for (int i = 0; i < cnt; ++i, s >>= 5) {
        int e   = (int)(s & 31);
        int cid = e >> 3;
        int m64 = e & 7;
        switch (cid) {
            case 0: conv_item<1, 0>(xs, wb + 0,      m64, bias1, 0, nt, hb, lane, lr, oct); break;
            case 1: conv_item<2, 0>(xs, wb + 102400, m64, bias2, 1, nt, hb, lane, lr, oct); break;
            case 2: conv_item<3, 1>(xs, wb + 307200, m64, bias3, 2, nt, hb, lane, lr, oct); break;
            default: conv_item<7, 3>(xs, wb + 614400, m64, bias7, 3, nt, hb, lane, lr, oct); break;
        }
    }
}

// ---------------- linear GEMM ----------------
// grid (256 n-tiles of 64, 2 h-halves), 256 threads = 4 waves = 4 h-slices of 64.
// All 4 waves issue IDENTICAL h-frag addresses (L1 dedup). Barrier-free, LDS-free,
// ping-pong register buffers one chunk ahead (vmcnt never drains).
__global__ __launch_bounds__(256, 2) void linear_kernel(
        const __hip_bfloat16* __restrict__ hbufg, const __hip_bfloat16* __restrict__ Wcg,
        const float* __restrict__ slp_b, float* __restrict__ out) {
    const int tid  = threadIdx.x;
    const int lane = tid & 63;
    const int wave = tid >> 6;
    const int lr   = lane & 31;
    const int oct  = lane >> 5;

    const int nt64 = blockIdx.x;                 // 0..255
    const int hw   = blockIdx.y * 4 + wave;      // 0..7
    const int mt4  = hw >> 1;
    const int mq0  = (hw & 1) * 2;

    const short* hb = (const short*)hbufg;
    const short* wc = (const short*)Wcg;

    floatx16 acc[2][2];   // [mi][ni]
#pragma unroll
    for (int i = 0; i < 2; i++)
#pragma unroll
        for (int j = 0; j < 2; j++)
#pragma unroll
            for (int r = 0; r < 16; r++) acc[i][j][r] = 0.f;

    short8 wf[2][8], hf[2][8];

#define LOAD_CHUNK(ch, p)                                                                 \
    {                                                                                     \
        _Pragma("unroll")                                                                 \
        for (int ks = 0; ks < 4; ++ks)                                                    \
            _Pragma("unroll")                                                             \
            for (int ni = 0; ni < 2; ++ni)                                                \
                hf[p][ks * 2 + ni] = *(const short8*)                                     \
                    &hb[(((nt64 * 2 + ni) * 76) + (ch) * 4 + ks) * 512 + lane * 8];       \
        _Pragma("unroll")                                                                 \
        for (int ks = 0; ks < 4; ++ks)                                                    \
            _Pragma("unroll")                                                             \
            for (int mi = 0; mi < 2; ++mi)                                                \
                wf[p][ks * 2 + mi] = *(const short8*)                                     \
                    &wc[((mt4 * 19 + (ch)) * 16 + ks * 4 + mq0 + mi) * 512 + lane * 8];   \
    }

    LOAD_CHUNK(0, 0)
#pragma unroll
    for (int ch = 0; ch < 19; ++ch) {
        const int p = ch & 1;
        if (ch < 18) LOAD_CHUNK(ch + 1, p ^ 1)
#pragma unroll
        for (int ks = 0; ks < 4; ++ks) {
            acc[0][0] = MFMA(wf[p][ks * 2 + 0], hf[p][ks * 2 + 0], acc[0][0], 0, 0, 0);
            acc[0][1] = MFMA(wf[p][ks * 2 + 0], hf[p][ks * 2 + 1], acc[0][1], 0, 0, 0);
            acc[1][0] = MFMA(wf[p][ks * 2 + 1], hf[p][ks * 2 + 0], acc[1][0], 0, 0, 0);
            acc[1][1] = MFMA(wf[p][ks * 2 + 1], hf[p][ks * 2 + 1], acc[1][1], 0, 0, 0);
        }
    }
#undef LOAD_CHUNK

    // D rows = h (regs), cols = n (lane&31): float4 stores (h fastest dim of out)
#pragma unroll
    for (int mi = 0; mi < 2; ++mi)
#pragma unroll
        for (int ni = 0; ni < 2; ++ni) {
            floatx16 v = acc[mi][ni];
            const int n = nt64 * 64 + ni * 32 + lr;
#pragma unroll
            for (int q = 0; q < 4; ++q) {
                int h0 = hw * 64 + mi * 32 + q * 8 + oct * 4;
                float4 bv = *(const float4*)&slp_b[h0];
                float4 o;
                o.x = fast_tanh(v[q * 4 + 0] + bv.x);
                o.y = fast_tanh(v[q * 4 + 1] + bv.y);
                o.z = fast_tanh(v[q * 4 + 2] + bv.z);
                o.w = fast_tanh(v[q * 4 + 3] + bv.w);
                *(float4*)&out[n * Hn + h0] = o;
            }
        }
}

// ---------------- launch ----------------

extern "C" void kernel_launch(void* const* d_in, const int* in_sizes, int n_in,
                              void* d_out, int out_size, void* d_ws, size_t ws_size,
                              hipStream_t stream) {
    const float* x     = (const float*)d_in[0];
    const float* w1    = (const float*)d_in[1];
    const float* b1    = (const float*)d_in[2];
    const float* w2    = (const float*)d_in[3];
    const float* b2    = (const float*)d_in[4];
    const float* w3    = (const float*)d_in[5];
    const float* b3    = (const float*)d_in[6];
    const float* w7    = (const float*)d_in[7];
    const float* b7    = (const float*)d_in[8];
    const float* slp_w = (const float*)d_in[9];
    const float* slp_b = (const float*)d_in[10];

    __hip_bfloat16* wsb = (__hip_bfloat16*)d_ws;

    const int prep_total = XB_ELEMS + WB_ELEMS + WC_ELEMS;   // 7,258,112
    prep_all<<<(prep_total + 255) / 256, 256, 0, stream>>>(x, w1, w2, w3, w7, slp_w, wsb);

    conv_kernel<<<dim3(256), 256, 0, stream>>>(wsb + XB_OFF, wsb + WB_OFF,
                                               b1, b2, b3, b7, wsb + HB_OFF);
    linear_kernel<<<dim3(256, 2), 256, 0, stream>>>(wsb + HB_OFF, wsb + WC_OFF,
                                                    slp_b, (float*)d_out);
}